// Round 7
// baseline (218.306 us; speedup 1.0000x reference)
//
#include <hip/hip_runtime.h>

#define DN 96
#define NCHUNK 256

typedef __attribute__((ext_vector_type(8))) short bf16x8;
typedef __attribute__((ext_vector_type(4))) float f32x4;

// ---------------------------------------------------------------------------
// helpers
// ---------------------------------------------------------------------------
__device__ __forceinline__ int edge_at(const void* ei, long long idx, int use64) {
    if (use64) return (int)((const long long*)ei)[idx];
    return ((const int*)ei)[idx];
}

__device__ __forceinline__ unsigned short f2bf(float f) {
    unsigned int u = __float_as_uint(f);
    return (unsigned short)((u + 0x7fffu + ((u >> 16) & 1u)) >> 16);  // RNE
}

// ---------------------------------------------------------------------------
// fused preprocessing (one kernel, NCHUNK blocks):
//  - per-block int64 detection (deterministic, identical in every block)
//  - edge compress to (src|dst<<16) for this block's chunk + LDS histogram
//  - grid-strided x->bf16 conversion and WT1/WT2/WT3 builds
//  - zeroes the bucket_scan last-block ticket
// ---------------------------------------------------------------------------
__global__ __launch_bounds__(256) void preprocess(
        const float* __restrict__ x, unsigned int* __restrict__ xb,
        const void* __restrict__ ei, unsigned int* __restrict__ eidx,
        int* __restrict__ hist,
        const float* __restrict__ W1r, const float* __restrict__ W1n,
        const float* __restrict__ W2r, const float* __restrict__ W2n,
        const float* __restrict__ lw, unsigned short* __restrict__ WT,
        int* __restrict__ donecnt,
        long long E, long long CE, int nbuck, int NP) {
    __shared__ int lh[800];
    __shared__ int flag;
    int c = blockIdx.x, tid = threadIdx.x;

    if (c == 0 && tid == 0) donecnt[0] = 0;

    // int64 detection: if input is int64, every high word is 0 (idx < 2^31).
    if (tid == 0) flag = 1;
    for (int b = tid; b < nbuck; b += 256) lh[b] = 0;
    __syncthreads();
    if (((const unsigned int*)ei)[2 * tid + 1] != 0u) atomicAnd(&flag, 0);
    __syncthreads();
    int use64 = flag;

    // this block's edge chunk: compress + histogram
    long long beg = (long long)c * CE;
    long long end = beg + CE; if (end > E) end = E;
    for (long long e = beg + tid; e < end; e += 256) {
        int s = edge_at(ei, e, use64);
        int d = edge_at(ei, E + e, use64);
        eidx[e] = (unsigned int)s | ((unsigned int)d << 16);
        atomicAdd(&lh[d >> 6], 1);
    }
    __syncthreads();
    for (int b = tid; b < nbuck; b += 256)
        hist[(size_t)c * nbuck + b] = lh[b];

    // x -> bf16 pairs (grid-strided)
    int gstride = gridDim.x * 256;
    for (int i = c * 256 + tid; i < NP; i += gstride) {
        float2 v = *(const float2*)(x + 2 * (size_t)i);
        xb[i] = (unsigned int)f2bf(v.x) | ((unsigned int)f2bf(v.y) << 16);
    }

    // WT builds (grid-strided over 3*96*192)
    for (int j = c * 256 + tid; j < 3 * DN * 192; j += gstride) {
        int w = j / (DN * 192);
        int r = j % (DN * 192);
        int jj = r / 192, k = r % 192;
        float v;
        if (w == 0)      v = (k < DN) ? W1r[(size_t)k * DN + jj] : W1n[(size_t)(k - DN) * DN + jj];
        else if (w == 1) v = (k < DN) ? W2r[(size_t)k * DN + jj] : W2n[(size_t)(k - DN) * DN + jj];
        else             v = lw[r];
        WT[j] = f2bf(v);
    }
}

// ---------------------------------------------------------------------------
// per-bucket: exclusive prefix over the 256 chunk counts (relative) + total;
// the last-arriving block then exclusive-scans btot in place (saves a launch).
// ---------------------------------------------------------------------------
__global__ __launch_bounds__(256) void bucket_scan(
        const int* __restrict__ hist, int* __restrict__ pos_rel,
        int* __restrict__ btot, int* __restrict__ donecnt, int nbuck) {
    __shared__ int wsum[4];
    __shared__ int lastflag;
    int b = blockIdx.x, tid = threadIdx.x;
    int lane = tid & 63, wid = tid >> 6;
    int v = hist[(size_t)tid * nbuck + b];
    int sv = v;
#pragma unroll
    for (int off = 1; off < 64; off <<= 1) {
        int t = __shfl_up(sv, off, 64);
        if (lane >= off) sv += t;
    }
    if (lane == 63) wsum[wid] = sv;
    __syncthreads();
    int woff = 0;
    for (int w = 0; w < wid; ++w) woff += wsum[w];
    pos_rel[(size_t)tid * nbuck + b] = woff + sv - v;
    if (tid == 255) btot[b] = woff + sv;

    // last-block-done: the final block scans btot
    __threadfence();
    if (tid == 0) {
        int t = atomicAdd(donecnt, 1);
        lastflag = (t == nbuck - 1);
    }
    __syncthreads();
    if (!lastflag) return;
    __threadfence();   // acquire: see all blocks' btot stores

    int carry = 0;
    for (int base = 0; base < nbuck; base += 256) {
        int i = base + tid;
        int bv = (i < nbuck) ? btot[i] : 0;
        int bs = bv;
#pragma unroll
        for (int off = 1; off < 64; off <<= 1) {
            int t = __shfl_up(bs, off, 64);
            if (lane >= off) bs += t;
        }
        __syncthreads();
        if (lane == 63) wsum[wid] = bs;
        __syncthreads();
        int woff2 = 0;
        for (int w = 0; w < wid; ++w) woff2 += wsum[w];
        int excl = carry + woff2 + bs - bv;
        if (i < nbuck) btot[i] = excl;
        carry += wsum[0] + wsum[1] + wsum[2] + wsum[3];
        __syncthreads();
    }
    if (tid == 0) btot[nbuck] = carry;
}

__global__ void scatter_grouped(const unsigned int* __restrict__ eidx, long long E,
                                const int* __restrict__ pos_rel,
                                const int* __restrict__ bstart,
                                unsigned int* __restrict__ packed,
                                int nbuck, long long CE) {
    __shared__ int cur[800];
    int c = blockIdx.x, tid = threadIdx.x;
    for (int b = tid; b < nbuck; b += 256)
        cur[b] = pos_rel[(size_t)c * nbuck + b] + bstart[b];
    __syncthreads();
    long long beg = (long long)c * CE;
    long long end = beg + CE; if (end > E) end = E;
    for (long long e = beg + tid; e < end; e += 256) {
        unsigned int u = eidx[e];
        int src = (int)(u & 0xFFFFu);
        int dst = (int)(u >> 16);
        int b = dst >> 6;
        int p = atomicAdd(&cur[b], 1);
        packed[p] = (unsigned int)src | ((unsigned int)(dst & 63) << 16);
    }
}

__global__ void bucket_sort(const unsigned int* __restrict__ packed,
                            const int* __restrict__ bstart,
                            unsigned short* __restrict__ csr_src,
                            int* __restrict__ rowptr, int n, int nbuck) {
    __shared__ int bin[64];
    __shared__ int cur[64];
    int b = blockIdx.x, tid = threadIdx.x;
    int beg = bstart[b], end = bstart[b + 1];
    if (tid < 64) bin[tid] = 0;
    __syncthreads();
    for (int i = beg + tid; i < end; i += 256)
        atomicAdd(&bin[packed[i] >> 16], 1);
    __syncthreads();
    if (tid < 64) {
        int v = bin[tid];
        int sv = v;
#pragma unroll
        for (int off = 1; off < 64; off <<= 1) {
            int t = __shfl_up(sv, off, 64);
            if (tid >= off) sv += t;
        }
        int excl = sv - v;
        cur[tid] = beg + excl;
        int node = b * 64 + tid;
        if (node < n) rowptr[node] = beg + excl;
    }
    __syncthreads();
    for (int i = beg + tid; i < end; i += 256) {
        unsigned int p = packed[i];
        int q = atomicAdd(&cur[p >> 16], 1);
        csr_src[q] = (unsigned short)(p & 0xFFFFu);
    }
    if (b == nbuck - 1 && tid == 0) rowptr[n] = end;
}

// ---------------------------------------------------------------------------
// CSR aggregation: bf16 in, fp32 accumulate, bf16 out. thread = (node, chunk
// of 8 values). Edge loop unrolled x8 with independent loads for MLP.
// ---------------------------------------------------------------------------
__device__ __forceinline__ void acc_row(float* acc, uint4 v) {
    unsigned int u;
    u = v.x; acc[0] += __uint_as_float(u << 16); acc[1] += __uint_as_float(u & 0xffff0000u);
    u = v.y; acc[2] += __uint_as_float(u << 16); acc[3] += __uint_as_float(u & 0xffff0000u);
    u = v.z; acc[4] += __uint_as_float(u << 16); acc[5] += __uint_as_float(u & 0xffff0000u);
    u = v.w; acc[6] += __uint_as_float(u << 16); acc[7] += __uint_as_float(u & 0xffff0000u);
}

__global__ void aggregate(const unsigned int* __restrict__ in, unsigned int* __restrict__ out,
                          const int* __restrict__ rowptr,
                          const unsigned short* __restrict__ srcs,
                          int n, int normalize) {
    int t = blockIdx.x * blockDim.x + threadIdx.x;
    if (t >= n * 12) return;
    int node = t / 12, c = t % 12;
    int beg = rowptr[node], end = rowptr[node + 1];
    float acc[8];
#pragma unroll
    for (int j = 0; j < 8; ++j) acc[j] = 0.f;
    int i = beg;
    for (; i + 8 <= end; i += 8) {
        int s[8];
        uint4 v[8];
#pragma unroll
        for (int j = 0; j < 8; ++j) s[j] = srcs[i + j];
#pragma unroll
        for (int j = 0; j < 8; ++j) v[j] = *(const uint4*)(in + (size_t)s[j] * 48 + c * 4);
#pragma unroll
        for (int j = 0; j < 8; ++j) acc_row(acc, v[j]);
    }
    if (i + 4 <= end) {
        int s0 = srcs[i], s1 = srcs[i + 1], s2 = srcs[i + 2], s3 = srcs[i + 3];
        uint4 v0 = *(const uint4*)(in + (size_t)s0 * 48 + c * 4);
        uint4 v1 = *(const uint4*)(in + (size_t)s1 * 48 + c * 4);
        uint4 v2 = *(const uint4*)(in + (size_t)s2 * 48 + c * 4);
        uint4 v3 = *(const uint4*)(in + (size_t)s3 * 48 + c * 4);
        acc_row(acc, v0); acc_row(acc, v1); acc_row(acc, v2); acc_row(acc, v3);
        i += 4;
    }
    for (; i < end; ++i) {
        uint4 v = *(const uint4*)(in + (size_t)srcs[i] * 48 + c * 4);
        acc_row(acc, v);
    }
    if (normalize) {
        float inv = 1.0f / fmaxf((float)(end - beg), 1.0f);
#pragma unroll
        for (int j = 0; j < 8; ++j) acc[j] *= inv;
    }
    uint4 r;
    r.x = (unsigned int)f2bf(acc[0]) | ((unsigned int)f2bf(acc[1]) << 16);
    r.y = (unsigned int)f2bf(acc[2]) | ((unsigned int)f2bf(acc[3]) << 16);
    r.z = (unsigned int)f2bf(acc[4]) | ((unsigned int)f2bf(acc[5]) << 16);
    r.w = (unsigned int)f2bf(acc[6]) | ((unsigned int)f2bf(acc[7]) << 16);
    *(uint4*)(out + (size_t)node * 48 + c * 4) = r;
}

// ---------------------------------------------------------------------------
// MFMA GEMM (proven structure): out[n,j] = [A|B][n,k]@WT[j,k]^T + bias
// WT staged in LDS [96][100] uints. Block: 4 waves x 32 rows = 128.
// ---------------------------------------------------------------------------
__global__ __launch_bounds__(256) void gemm_mfma(
        const unsigned short* __restrict__ Abf, const unsigned short* __restrict__ Bbf,
        const unsigned short* __restrict__ WT, const float* __restrict__ bias,
        float* __restrict__ outf, unsigned short* __restrict__ outb,
        int n, int dorelu) {
    __shared__ unsigned int WTl[DN * 100];   // [96][100] uints
    int tid = threadIdx.x;
    const unsigned int* WTg = (const unsigned int*)WT;   // [96][96] uints
    for (int i = tid; i < DN * 96; i += 256) {
        int j = i / 96, m = i - j * 96;
        WTl[j * 100 + m] = WTg[i];
    }
    __syncthreads();

    int wid = tid >> 6, lane = tid & 63;
    int lg = lane >> 4, lr = lane & 15;
    int rowbase = blockIdx.x * 128 + wid * 32;

    f32x4 acc[2][6];
#pragma unroll
    for (int rt = 0; rt < 2; ++rt)
#pragma unroll
        for (int ct = 0; ct < 6; ++ct) acc[rt][ct] = (f32x4){0.f, 0.f, 0.f, 0.f};

    const unsigned short* WTs = (const unsigned short*)WTl;
#pragma unroll
    for (int kt = 0; kt < 6; ++kt) {
        const unsigned short* src = (kt < 3) ? Abf : Bbf;
        int kk = (kt < 3 ? kt : kt - 3) * 32 + lg * 8;
        bf16x8 afrag[2];
#pragma unroll
        for (int rt = 0; rt < 2; ++rt) {
            int row = rowbase + rt * 16 + lr;
            if (row >= n) row = n - 1;
            afrag[rt] = *(const bf16x8*)(src + (size_t)row * DN + kk);
        }
        int koff = kt * 32 + lg * 8;
#pragma unroll
        for (int ct = 0; ct < 6; ++ct) {
            bf16x8 bfrag = *(const bf16x8*)(WTs + (ct * 16 + lr) * 200 + koff);
            acc[0][ct] = __builtin_amdgcn_mfma_f32_16x16x32_bf16(afrag[0], bfrag, acc[0][ct], 0, 0, 0);
            acc[1][ct] = __builtin_amdgcn_mfma_f32_16x16x32_bf16(afrag[1], bfrag, acc[1][ct], 0, 0, 0);
        }
    }

#pragma unroll
    for (int ct = 0; ct < 6; ++ct) {
        int col = ct * 16 + lr;
        float bv = bias[col];
#pragma unroll
        for (int rt = 0; rt < 2; ++rt)
#pragma unroll
            for (int r = 0; r < 4; ++r) {
                int row = rowbase + rt * 16 + lg * 4 + r;
                if (row < n) {
                    float v = acc[rt][ct][r] + bv;
                    if (dorelu) v = fmaxf(v, 0.f);
                    if (outf) outf[(size_t)row * DN + col] = v;
                    if (outb) outb[(size_t)row * DN + col] = f2bf(v);
                }
            }
    }
}

// ---------------------------------------------------------------------------
// Fused conv2 + final linear, LDS-staged weights (re-staged between stages).
// ---------------------------------------------------------------------------
__global__ __launch_bounds__(256) void gemm_fused(
        const unsigned short* __restrict__ h1, const unsigned short* __restrict__ agg,
        const unsigned short* __restrict__ WT2, const float* __restrict__ b2,
        const unsigned short* __restrict__ WT3, const float* __restrict__ lb,
        float* __restrict__ out, int n) {
    __shared__ unsigned int WTl[DN * 100];     // [96][100] uints
    __shared__ unsigned short h2t[4][32][98];  // per-wave 32-row h2 tile
    int tid = threadIdx.x, wid = tid >> 6, lane = tid & 63;
    int lg = lane >> 4, lr = lane & 15;
    int rowbase = blockIdx.x * 128 + wid * 32;

    const unsigned int* WTg2 = (const unsigned int*)WT2;
    for (int i = tid; i < DN * 96; i += 256) {
        int j = i / 96, m = i - j * 96;
        WTl[j * 100 + m] = WTg2[i];
    }
    __syncthreads();

    f32x4 acc[2][6];
#pragma unroll
    for (int rt = 0; rt < 2; ++rt)
#pragma unroll
        for (int ct = 0; ct < 6; ++ct) acc[rt][ct] = (f32x4){0.f, 0.f, 0.f, 0.f};

    const unsigned short* WTs = (const unsigned short*)WTl;
    bf16x8 afragA[2][3];   // h1 fragments, reused in stage 2
#pragma unroll
    for (int kt = 0; kt < 6; ++kt) {
        bf16x8 afrag[2];
#pragma unroll
        for (int rt = 0; rt < 2; ++rt) {
            int row = rowbase + rt * 16 + lr;
            if (row >= n) row = n - 1;
            if (kt < 3) {
                afrag[rt] = *(const bf16x8*)(h1 + (size_t)row * DN + kt * 32 + lg * 8);
                afragA[rt][kt] = afrag[rt];
            } else {
                afrag[rt] = *(const bf16x8*)(agg + (size_t)row * DN + (kt - 3) * 32 + lg * 8);
            }
        }
        int koff = kt * 32 + lg * 8;
#pragma unroll
        for (int ct = 0; ct < 6; ++ct) {
            bf16x8 bfrag = *(const bf16x8*)(WTs + (ct * 16 + lr) * 200 + koff);
            acc[0][ct] = __builtin_amdgcn_mfma_f32_16x16x32_bf16(afrag[0], bfrag, acc[0][ct], 0, 0, 0);
            acc[1][ct] = __builtin_amdgcn_mfma_f32_16x16x32_bf16(afrag[1], bfrag, acc[1][ct], 0, 0, 0);
        }
    }

    // h2 (bias added, no relu) -> LDS tile, C/D layout -> row-major
#pragma unroll
    for (int ct = 0; ct < 6; ++ct) {
        float bv = b2[ct * 16 + lr];
#pragma unroll
        for (int rt = 0; rt < 2; ++rt)
#pragma unroll
            for (int r = 0; r < 4; ++r)
                h2t[wid][rt * 16 + lg * 4 + r][ct * 16 + lr] = f2bf(acc[rt][ct][r] + bv);
    }
    __syncthreads();   // all waves done reading WT2, h2t complete

    // re-stage WT3 into the same LDS buffer
    const unsigned int* WTg3 = (const unsigned int*)WT3;
    for (int i = tid; i < DN * 96; i += 256) {
        int j = i / 96, m = i - j * 96;
        WTl[j * 100 + m] = WTg3[i];
    }
    __syncthreads();

    f32x4 acc2[2][6];
#pragma unroll
    for (int rt = 0; rt < 2; ++rt)
#pragma unroll
        for (int ct = 0; ct < 6; ++ct) acc2[rt][ct] = (f32x4){0.f, 0.f, 0.f, 0.f};

#pragma unroll
    for (int kt = 0; kt < 6; ++kt) {
        bf16x8 afrag[2];
#pragma unroll
        for (int rt = 0; rt < 2; ++rt) {
            if (kt < 3) afrag[rt] = afragA[rt][kt];
            else        afrag[rt] = *(const bf16x8*)(&h2t[wid][rt * 16 + lr][(kt - 3) * 32 + lg * 8]);
        }
        int koff = kt * 32 + lg * 8;
#pragma unroll
        for (int ct = 0; ct < 6; ++ct) {
            bf16x8 bfrag = *(const bf16x8*)(WTs + (ct * 16 + lr) * 200 + koff);
            acc2[0][ct] = __builtin_amdgcn_mfma_f32_16x16x32_bf16(afrag[0], bfrag, acc2[0][ct], 0, 0, 0);
            acc2[1][ct] = __builtin_amdgcn_mfma_f32_16x16x32_bf16(afrag[1], bfrag, acc2[1][ct], 0, 0, 0);
        }
    }

#pragma unroll
    for (int ct = 0; ct < 6; ++ct) {
        int col = ct * 16 + lr;
        float bv = lb[col];
#pragma unroll
        for (int rt = 0; rt < 2; ++rt)
#pragma unroll
            for (int r = 0; r < 4; ++r) {
                int row = rowbase + rt * 16 + lg * 4 + r;
                if (row < n)
                    out[(size_t)row * DN + col] = fmaxf(acc2[rt][ct][r] + bv, 0.f);
            }
    }
}

// ---------------------------------------------------------------------------
extern "C" void kernel_launch(void* const* d_in, const int* in_sizes, int n_in,
                              void* d_out, int out_size, void* d_ws, size_t ws_size,
                              hipStream_t stream) {
    const float* x   = (const float*)d_in[0];
    const void*  ei  = d_in[1];
    const float* W1r = (const float*)d_in[2];
    const float* W1n = (const float*)d_in[3];
    const float* b1  = (const float*)d_in[4];
    const float* W2r = (const float*)d_in[5];
    const float* W2n = (const float*)d_in[6];
    const float* b2  = (const float*)d_in[7];
    const float* lw  = (const float*)d_in[8];
    const float* lb  = (const float*)d_in[9];
    float* out = (float*)d_out;

    const int N = in_sizes[0] / DN;         // 50000
    const long long E = in_sizes[1] / 2;    // 800000
    const int NBUCK = (N + 63) / 64;        // 782
    const long long CE = (E + NCHUNK - 1) / NCHUNK;
    const size_t NP = (size_t)N * 48;       // bf16-pair uints per feature map

    unsigned int* xb   = (unsigned int*)d_ws;        // [N*48]
    unsigned int* h1b  = xb + NP;                    // [N*48]
    unsigned int* aggb = h1b + NP;                   // [N*48]
    unsigned short* WT = (unsigned short*)(aggb + NP);    // [3*96*192]
    unsigned short* WT1 = WT;
    unsigned short* WT2 = WT + DN * 192;
    unsigned short* WT3 = WT2 + DN * 192;
    unsigned int* eidx = (unsigned int*)(WT3 + DN * 192); // [E]
    int* hist   = (int*)(eidx + E);                  // [NCHUNK*NBUCK]
    int* pos    = hist + NCHUNK * NBUCK;             // [NCHUNK*NBUCK] relative
    int* btot   = pos + NCHUNK * NBUCK;              // [NBUCK+1] -> bstart
    int* rowptr = btot + NBUCK + 1;                  // [N+1]
    unsigned int* packed = (unsigned int*)(rowptr + N + 1);  // [E]
    unsigned short* csr_src = (unsigned short*)(packed + E); // [E]
    int* donecnt = (int*)(csr_src + E);              // [1]

    preprocess<<<NCHUNK, 256, 0, stream>>>(x, xb, ei, eidx, hist,
                                           W1r, W1n, W2r, W2n, lw, WT, donecnt,
                                           E, CE, NBUCK, (int)NP);
    bucket_scan<<<NBUCK, 256, 0, stream>>>(hist, pos, btot, donecnt, NBUCK);
    scatter_grouped<<<NCHUNK, 256, 0, stream>>>(eidx, E, pos, btot, packed, NBUCK, CE);
    bucket_sort<<<NBUCK, 256, 0, stream>>>(packed, btot, csr_src, rowptr, N, NBUCK);

    int ab = (N * 12 + 255) / 256;
    int gb = (N + 127) / 128;

    // conv1: h1 = x@W1r + agg(x)@W1n + b1  (bf16 out only)
    aggregate<<<ab, 256, 0, stream>>>(xb, aggb, rowptr, csr_src, N, 0);
    gemm_mfma<<<gb, 256, 0, stream>>>((const unsigned short*)xb, (const unsigned short*)aggb,
                                      WT1, b1, (float*)0, (unsigned short*)h1b, N, 0);
    // conv2 + linear fused: out = relu([h1 | h1@W2r+agg(h1)/deg@W2n+b2] @ lin^T + lb)
    aggregate<<<ab, 256, 0, stream>>>(h1b, aggb, rowptr, csr_src, N, 1);
    gemm_fused<<<gb, 256, 0, stream>>>((const unsigned short*)h1b, (const unsigned short*)aggb,
                                       WT2, b2, WT3, lb, out, N);
}

// Round 8
// 122.606 us; speedup vs baseline: 1.7805x; 1.7805x over previous
//
#include <hip/hip_runtime.h>

#define DN 96
#define NCHUNK 256

typedef __attribute__((ext_vector_type(8))) short bf16x8;
typedef __attribute__((ext_vector_type(4))) float f32x4;

// ---------------------------------------------------------------------------
// helpers
// ---------------------------------------------------------------------------
__device__ __forceinline__ int edge_at(const void* ei, long long idx, int use64) {
    if (use64) return (int)((const long long*)ei)[idx];
    return ((const int*)ei)[idx];
}

__device__ __forceinline__ unsigned short f2bf(float f) {
    unsigned int u = __float_as_uint(f);
    return (unsigned short)((u + 0x7fffu + ((u >> 16) & 1u)) >> 16);  // RNE
}

// ---------------------------------------------------------------------------
// fused preprocessing (one kernel, NCHUNK blocks):
//  - per-block int64 detection (deterministic, identical in every block)
//  - edge compress to (src|dst<<16) for this block's chunk + LDS histogram
//  - grid-strided x->bf16 conversion and WT1/WT2/WT3 builds
// ---------------------------------------------------------------------------
__global__ __launch_bounds__(256) void preprocess(
        const float* __restrict__ x, unsigned int* __restrict__ xb,
        const void* __restrict__ ei, unsigned int* __restrict__ eidx,
        int* __restrict__ hist,
        const float* __restrict__ W1r, const float* __restrict__ W1n,
        const float* __restrict__ W2r, const float* __restrict__ W2n,
        const float* __restrict__ lw, unsigned short* __restrict__ WT,
        long long E, long long CE, int nbuck, int NP) {
    __shared__ int lh[800];
    __shared__ int flag;
    int c = blockIdx.x, tid = threadIdx.x;

    // int64 detection: if input is int64, every high word is 0 (idx < 2^31).
    if (tid == 0) flag = 1;
    for (int b = tid; b < nbuck; b += 256) lh[b] = 0;
    __syncthreads();
    if (((const unsigned int*)ei)[2 * tid + 1] != 0u) atomicAnd(&flag, 0);
    __syncthreads();
    int use64 = flag;

    // this block's edge chunk: compress + histogram
    long long beg = (long long)c * CE;
    long long end = beg + CE; if (end > E) end = E;
    for (long long e = beg + tid; e < end; e += 256) {
        int s = edge_at(ei, e, use64);
        int d = edge_at(ei, E + e, use64);
        eidx[e] = (unsigned int)s | ((unsigned int)d << 16);
        atomicAdd(&lh[d >> 6], 1);
    }
    __syncthreads();
    for (int b = tid; b < nbuck; b += 256)
        hist[(size_t)c * nbuck + b] = lh[b];

    // x -> bf16 pairs (grid-strided)
    int gstride = gridDim.x * 256;
    for (int i = c * 256 + tid; i < NP; i += gstride) {
        float2 v = *(const float2*)(x + 2 * (size_t)i);
        xb[i] = (unsigned int)f2bf(v.x) | ((unsigned int)f2bf(v.y) << 16);
    }

    // WT builds (grid-strided over 3*96*192)
    for (int j = c * 256 + tid; j < 3 * DN * 192; j += gstride) {
        int w = j / (DN * 192);
        int r = j % (DN * 192);
        int jj = r / 192, k = r % 192;
        float v;
        if (w == 0)      v = (k < DN) ? W1r[(size_t)k * DN + jj] : W1n[(size_t)(k - DN) * DN + jj];
        else if (w == 1) v = (k < DN) ? W2r[(size_t)k * DN + jj] : W2n[(size_t)(k - DN) * DN + jj];
        else             v = lw[r];
        WT[j] = f2bf(v);
    }
}

// ---------------------------------------------------------------------------
// per-bucket: exclusive prefix over the 256 chunk counts (relative) + total
// (round-6 version: no fences, no cross-block signalling)
// ---------------------------------------------------------------------------
__global__ void bucket_scan(const int* __restrict__ hist, int* __restrict__ pos_rel,
                            int* __restrict__ btot, int nbuck) {
    __shared__ int wsum[4];
    int b = blockIdx.x, tid = threadIdx.x;
    int lane = tid & 63, wid = tid >> 6;
    int v = hist[(size_t)tid * nbuck + b];
    int sv = v;
#pragma unroll
    for (int off = 1; off < 64; off <<= 1) {
        int t = __shfl_up(sv, off, 64);
        if (lane >= off) sv += t;
    }
    if (lane == 63) wsum[wid] = sv;
    __syncthreads();
    int woff = 0;
    for (int w = 0; w < wid; ++w) woff += wsum[w];
    pos_rel[(size_t)tid * nbuck + b] = woff + sv - v;
    if (tid == 255) btot[b] = woff + sv;
}

// single block exclusive scan, in place; data[n] = total
__global__ void scan_excl(int* data, int n) {
    __shared__ int swsum[16];
    int tid = threadIdx.x;
    int lane = tid & 63, wid = tid >> 6;
    int carry = 0;
    for (int base = 0; base < n; base += 1024) {
        int i = base + tid;
        int v = (i < n) ? data[i] : 0;
        int sv = v;
#pragma unroll
        for (int off = 1; off < 64; off <<= 1) {
            int t = __shfl_up(sv, off, 64);
            if (lane >= off) sv += t;
        }
        __syncthreads();
        if (lane == 63) swsum[wid] = sv;
        __syncthreads();
        if (tid < 16) {
            int wv = swsum[tid];
#pragma unroll
            for (int off = 1; off < 16; off <<= 1) {
                int t = __shfl_up(wv, off, 16);
                if (tid >= off) wv += t;
            }
            swsum[tid] = wv;
        }
        __syncthreads();
        int woff = (wid > 0) ? swsum[wid - 1] : 0;
        int excl = carry + woff + sv - v;
        if (i < n) data[i] = excl;
        carry += swsum[15];
        __syncthreads();
    }
    if (tid == 0) data[n] = carry;
}

__global__ void scatter_grouped(const unsigned int* __restrict__ eidx, long long E,
                                const int* __restrict__ pos_rel,
                                const int* __restrict__ bstart,
                                unsigned int* __restrict__ packed,
                                int nbuck, long long CE) {
    __shared__ int cur[800];
    int c = blockIdx.x, tid = threadIdx.x;
    for (int b = tid; b < nbuck; b += 256)
        cur[b] = pos_rel[(size_t)c * nbuck + b] + bstart[b];
    __syncthreads();
    long long beg = (long long)c * CE;
    long long end = beg + CE; if (end > E) end = E;
    for (long long e = beg + tid; e < end; e += 256) {
        unsigned int u = eidx[e];
        int src = (int)(u & 0xFFFFu);
        int dst = (int)(u >> 16);
        int b = dst >> 6;
        int p = atomicAdd(&cur[b], 1);
        packed[p] = (unsigned int)src | ((unsigned int)(dst & 63) << 16);
    }
}

__global__ void bucket_sort(const unsigned int* __restrict__ packed,
                            const int* __restrict__ bstart,
                            unsigned short* __restrict__ csr_src,
                            int* __restrict__ rowptr, int n, int nbuck) {
    __shared__ int bin[64];
    __shared__ int cur[64];
    int b = blockIdx.x, tid = threadIdx.x;
    int beg = bstart[b], end = bstart[b + 1];
    if (tid < 64) bin[tid] = 0;
    __syncthreads();
    for (int i = beg + tid; i < end; i += 256)
        atomicAdd(&bin[packed[i] >> 16], 1);
    __syncthreads();
    if (tid < 64) {
        int v = bin[tid];
        int sv = v;
#pragma unroll
        for (int off = 1; off < 64; off <<= 1) {
            int t = __shfl_up(sv, off, 64);
            if (tid >= off) sv += t;
        }
        int excl = sv - v;
        cur[tid] = beg + excl;
        int node = b * 64 + tid;
        if (node < n) rowptr[node] = beg + excl;
    }
    __syncthreads();
    for (int i = beg + tid; i < end; i += 256) {
        unsigned int p = packed[i];
        int q = atomicAdd(&cur[p >> 16], 1);
        csr_src[q] = (unsigned short)(p & 0xFFFFu);
    }
    if (b == nbuck - 1 && tid == 0) rowptr[n] = end;
}

// ---------------------------------------------------------------------------
// CSR aggregation: bf16 in, fp32 accumulate, bf16 out. thread = (node, chunk
// of 8 values). Edge loop unrolled x8 with independent loads for MLP.
// ---------------------------------------------------------------------------
__device__ __forceinline__ void acc_row(float* acc, uint4 v) {
    unsigned int u;
    u = v.x; acc[0] += __uint_as_float(u << 16); acc[1] += __uint_as_float(u & 0xffff0000u);
    u = v.y; acc[2] += __uint_as_float(u << 16); acc[3] += __uint_as_float(u & 0xffff0000u);
    u = v.z; acc[4] += __uint_as_float(u << 16); acc[5] += __uint_as_float(u & 0xffff0000u);
    u = v.w; acc[6] += __uint_as_float(u << 16); acc[7] += __uint_as_float(u & 0xffff0000u);
}

__global__ void aggregate(const unsigned int* __restrict__ in, unsigned int* __restrict__ out,
                          const int* __restrict__ rowptr,
                          const unsigned short* __restrict__ srcs,
                          int n, int normalize) {
    int t = blockIdx.x * blockDim.x + threadIdx.x;
    if (t >= n * 12) return;
    int node = t / 12, c = t % 12;
    int beg = rowptr[node], end = rowptr[node + 1];
    float acc[8];
#pragma unroll
    for (int j = 0; j < 8; ++j) acc[j] = 0.f;
    int i = beg;
    for (; i + 8 <= end; i += 8) {
        int s[8];
        uint4 v[8];
#pragma unroll
        for (int j = 0; j < 8; ++j) s[j] = srcs[i + j];
#pragma unroll
        for (int j = 0; j < 8; ++j) v[j] = *(const uint4*)(in + (size_t)s[j] * 48 + c * 4);
#pragma unroll
        for (int j = 0; j < 8; ++j) acc_row(acc, v[j]);
    }
    if (i + 4 <= end) {
        int s0 = srcs[i], s1 = srcs[i + 1], s2 = srcs[i + 2], s3 = srcs[i + 3];
        uint4 v0 = *(const uint4*)(in + (size_t)s0 * 48 + c * 4);
        uint4 v1 = *(const uint4*)(in + (size_t)s1 * 48 + c * 4);
        uint4 v2 = *(const uint4*)(in + (size_t)s2 * 48 + c * 4);
        uint4 v3 = *(const uint4*)(in + (size_t)s3 * 48 + c * 4);
        acc_row(acc, v0); acc_row(acc, v1); acc_row(acc, v2); acc_row(acc, v3);
        i += 4;
    }
    for (; i < end; ++i) {
        uint4 v = *(const uint4*)(in + (size_t)srcs[i] * 48 + c * 4);
        acc_row(acc, v);
    }
    if (normalize) {
        float inv = 1.0f / fmaxf((float)(end - beg), 1.0f);
#pragma unroll
        for (int j = 0; j < 8; ++j) acc[j] *= inv;
    }
    uint4 r;
    r.x = (unsigned int)f2bf(acc[0]) | ((unsigned int)f2bf(acc[1]) << 16);
    r.y = (unsigned int)f2bf(acc[2]) | ((unsigned int)f2bf(acc[3]) << 16);
    r.z = (unsigned int)f2bf(acc[4]) | ((unsigned int)f2bf(acc[5]) << 16);
    r.w = (unsigned int)f2bf(acc[6]) | ((unsigned int)f2bf(acc[7]) << 16);
    *(uint4*)(out + (size_t)node * 48 + c * 4) = r;
}

// ---------------------------------------------------------------------------
// MFMA GEMM (proven structure): out[n,j] = [A|B][n,k]@WT[j,k]^T + bias
// WT staged in LDS [96][100] uints. Block: 4 waves x 32 rows = 128.
// ---------------------------------------------------------------------------
__global__ __launch_bounds__(256) void gemm_mfma(
        const unsigned short* __restrict__ Abf, const unsigned short* __restrict__ Bbf,
        const unsigned short* __restrict__ WT, const float* __restrict__ bias,
        float* __restrict__ outf, unsigned short* __restrict__ outb,
        int n, int dorelu) {
    __shared__ unsigned int WTl[DN * 100];   // [96][100] uints
    int tid = threadIdx.x;
    const unsigned int* WTg = (const unsigned int*)WT;   // [96][96] uints
    for (int i = tid; i < DN * 96; i += 256) {
        int j = i / 96, m = i - j * 96;
        WTl[j * 100 + m] = WTg[i];
    }
    __syncthreads();

    int wid = tid >> 6, lane = tid & 63;
    int lg = lane >> 4, lr = lane & 15;
    int rowbase = blockIdx.x * 128 + wid * 32;

    f32x4 acc[2][6];
#pragma unroll
    for (int rt = 0; rt < 2; ++rt)
#pragma unroll
        for (int ct = 0; ct < 6; ++ct) acc[rt][ct] = (f32x4){0.f, 0.f, 0.f, 0.f};

    const unsigned short* WTs = (const unsigned short*)WTl;
#pragma unroll
    for (int kt = 0; kt < 6; ++kt) {
        const unsigned short* src = (kt < 3) ? Abf : Bbf;
        int kk = (kt < 3 ? kt : kt - 3) * 32 + lg * 8;
        bf16x8 afrag[2];
#pragma unroll
        for (int rt = 0; rt < 2; ++rt) {
            int row = rowbase + rt * 16 + lr;
            if (row >= n) row = n - 1;
            afrag[rt] = *(const bf16x8*)(src + (size_t)row * DN + kk);
        }
        int koff = kt * 32 + lg * 8;
#pragma unroll
        for (int ct = 0; ct < 6; ++ct) {
            bf16x8 bfrag = *(const bf16x8*)(WTs + (ct * 16 + lr) * 200 + koff);
            acc[0][ct] = __builtin_amdgcn_mfma_f32_16x16x32_bf16(afrag[0], bfrag, acc[0][ct], 0, 0, 0);
            acc[1][ct] = __builtin_amdgcn_mfma_f32_16x16x32_bf16(afrag[1], bfrag, acc[1][ct], 0, 0, 0);
        }
    }

#pragma unroll
    for (int ct = 0; ct < 6; ++ct) {
        int col = ct * 16 + lr;
        float bv = bias[col];
#pragma unroll
        for (int rt = 0; rt < 2; ++rt)
#pragma unroll
            for (int r = 0; r < 4; ++r) {
                int row = rowbase + rt * 16 + lg * 4 + r;
                if (row < n) {
                    float v = acc[rt][ct][r] + bv;
                    if (dorelu) v = fmaxf(v, 0.f);
                    if (outf) outf[(size_t)row * DN + col] = v;
                    if (outb) outb[(size_t)row * DN + col] = f2bf(v);
                }
            }
    }
}

// ---------------------------------------------------------------------------
// Fused conv2 + final linear, LDS-staged weights (re-staged between stages).
// ---------------------------------------------------------------------------
__global__ __launch_bounds__(256) void gemm_fused(
        const unsigned short* __restrict__ h1, const unsigned short* __restrict__ agg,
        const unsigned short* __restrict__ WT2, const float* __restrict__ b2,
        const unsigned short* __restrict__ WT3, const float* __restrict__ lb,
        float* __restrict__ out, int n) {
    __shared__ unsigned int WTl[DN * 100];     // [96][100] uints
    __shared__ unsigned short h2t[4][32][98];  // per-wave 32-row h2 tile
    int tid = threadIdx.x, wid = tid >> 6, lane = tid & 63;
    int lg = lane >> 4, lr = lane & 15;
    int rowbase = blockIdx.x * 128 + wid * 32;

    const unsigned int* WTg2 = (const unsigned int*)WT2;
    for (int i = tid; i < DN * 96; i += 256) {
        int j = i / 96, m = i - j * 96;
        WTl[j * 100 + m] = WTg2[i];
    }
    __syncthreads();

    f32x4 acc[2][6];
#pragma unroll
    for (int rt = 0; rt < 2; ++rt)
#pragma unroll
        for (int ct = 0; ct < 6; ++ct) acc[rt][ct] = (f32x4){0.f, 0.f, 0.f, 0.f};

    const unsigned short* WTs = (const unsigned short*)WTl;
    bf16x8 afragA[2][3];   // h1 fragments, reused in stage 2
#pragma unroll
    for (int kt = 0; kt < 6; ++kt) {
        bf16x8 afrag[2];
#pragma unroll
        for (int rt = 0; rt < 2; ++rt) {
            int row = rowbase + rt * 16 + lr;
            if (row >= n) row = n - 1;
            if (kt < 3) {
                afrag[rt] = *(const bf16x8*)(h1 + (size_t)row * DN + kt * 32 + lg * 8);
                afragA[rt][kt] = afrag[rt];
            } else {
                afrag[rt] = *(const bf16x8*)(agg + (size_t)row * DN + (kt - 3) * 32 + lg * 8);
            }
        }
        int koff = kt * 32 + lg * 8;
#pragma unroll
        for (int ct = 0; ct < 6; ++ct) {
            bf16x8 bfrag = *(const bf16x8*)(WTs + (ct * 16 + lr) * 200 + koff);
            acc[0][ct] = __builtin_amdgcn_mfma_f32_16x16x32_bf16(afrag[0], bfrag, acc[0][ct], 0, 0, 0);
            acc[1][ct] = __builtin_amdgcn_mfma_f32_16x16x32_bf16(afrag[1], bfrag, acc[1][ct], 0, 0, 0);
        }
    }

    // h2 (bias added, no relu) -> LDS tile, C/D layout -> row-major
#pragma unroll
    for (int ct = 0; ct < 6; ++ct) {
        float bv = b2[ct * 16 + lr];
#pragma unroll
        for (int rt = 0; rt < 2; ++rt)
#pragma unroll
            for (int r = 0; r < 4; ++r)
                h2t[wid][rt * 16 + lg * 4 + r][ct * 16 + lr] = f2bf(acc[rt][ct][r] + bv);
    }
    __syncthreads();   // all waves done reading WT2, h2t complete

    // re-stage WT3 into the same LDS buffer
    const unsigned int* WTg3 = (const unsigned int*)WT3;
    for (int i = tid; i < DN * 96; i += 256) {
        int j = i / 96, m = i - j * 96;
        WTl[j * 100 + m] = WTg3[i];
    }
    __syncthreads();

    f32x4 acc2[2][6];
#pragma unroll
    for (int rt = 0; rt < 2; ++rt)
#pragma unroll
        for (int ct = 0; ct < 6; ++ct) acc2[rt][ct] = (f32x4){0.f, 0.f, 0.f, 0.f};

#pragma unroll
    for (int kt = 0; kt < 6; ++kt) {
        bf16x8 afrag[2];
#pragma unroll
        for (int rt = 0; rt < 2; ++rt) {
            if (kt < 3) afrag[rt] = afragA[rt][kt];
            else        afrag[rt] = *(const bf16x8*)(&h2t[wid][rt * 16 + lr][(kt - 3) * 32 + lg * 8]);
        }
        int koff = kt * 32 + lg * 8;
#pragma unroll
        for (int ct = 0; ct < 6; ++ct) {
            bf16x8 bfrag = *(const bf16x8*)(WTs + (ct * 16 + lr) * 200 + koff);
            acc2[0][ct] = __builtin_amdgcn_mfma_f32_16x16x32_bf16(afrag[0], bfrag, acc2[0][ct], 0, 0, 0);
            acc2[1][ct] = __builtin_amdgcn_mfma_f32_16x16x32_bf16(afrag[1], bfrag, acc2[1][ct], 0, 0, 0);
        }
    }

#pragma unroll
    for (int ct = 0; ct < 6; ++ct) {
        int col = ct * 16 + lr;
        float bv = lb[col];
#pragma unroll
        for (int rt = 0; rt < 2; ++rt)
#pragma unroll
            for (int r = 0; r < 4; ++r) {
                int row = rowbase + rt * 16 + lg * 4 + r;
                if (row < n)
                    out[(size_t)row * DN + col] = fmaxf(acc2[rt][ct][r] + bv, 0.f);
            }
    }
}

// ---------------------------------------------------------------------------
extern "C" void kernel_launch(void* const* d_in, const int* in_sizes, int n_in,
                              void* d_out, int out_size, void* d_ws, size_t ws_size,
                              hipStream_t stream) {
    const float* x   = (const float*)d_in[0];
    const void*  ei  = d_in[1];
    const float* W1r = (const float*)d_in[2];
    const float* W1n = (const float*)d_in[3];
    const float* b1  = (const float*)d_in[4];
    const float* W2r = (const float*)d_in[5];
    const float* W2n = (const float*)d_in[6];
    const float* b2  = (const float*)d_in[7];
    const float* lw  = (const float*)d_in[8];
    const float* lb  = (const float*)d_in[9];
    float* out = (float*)d_out;

    const int N = in_sizes[0] / DN;         // 50000
    const long long E = in_sizes[1] / 2;    // 800000
    const int NBUCK = (N + 63) / 64;        // 782
    const long long CE = (E + NCHUNK - 1) / NCHUNK;
    const size_t NP = (size_t)N * 48;       // bf16-pair uints per feature map

    unsigned int* xb   = (unsigned int*)d_ws;        // [N*48]
    unsigned int* h1b  = xb + NP;                    // [N*48]
    unsigned int* aggb = h1b + NP;                   // [N*48]
    unsigned short* WT = (unsigned short*)(aggb + NP);    // [3*96*192]
    unsigned short* WT1 = WT;
    unsigned short* WT2 = WT + DN * 192;
    unsigned short* WT3 = WT2 + DN * 192;
    unsigned int* eidx = (unsigned int*)(WT3 + DN * 192); // [E]
    int* hist   = (int*)(eidx + E);                  // [NCHUNK*NBUCK]
    int* pos    = hist + NCHUNK * NBUCK;             // [NCHUNK*NBUCK] relative
    int* btot   = pos + NCHUNK * NBUCK;              // [NBUCK+1] -> bstart
    int* rowptr = btot + NBUCK + 1;                  // [N+1]
    unsigned int* packed = (unsigned int*)(rowptr + N + 1);  // [E]
    unsigned short* csr_src = (unsigned short*)(packed + E); // [E]

    preprocess<<<NCHUNK, 256, 0, stream>>>(x, xb, ei, eidx, hist,
                                           W1r, W1n, W2r, W2n, lw, WT,
                                           E, CE, NBUCK, (int)NP);
    bucket_scan<<<NBUCK, 256, 0, stream>>>(hist, pos, btot, NBUCK);
    scan_excl<<<1, 1024, 0, stream>>>(btot, NBUCK);
    scatter_grouped<<<NCHUNK, 256, 0, stream>>>(eidx, E, pos, btot, packed, NBUCK, CE);
    bucket_sort<<<NBUCK, 256, 0, stream>>>(packed, btot, csr_src, rowptr, N, NBUCK);

    int ab = (N * 12 + 255) / 256;
    int gb = (N + 127) / 128;

    // conv1: h1 = x@W1r + agg(x)@W1n + b1  (bf16 out only)
    aggregate<<<ab, 256, 0, stream>>>(xb, aggb, rowptr, csr_src, N, 0);
    gemm_mfma<<<gb, 256, 0, stream>>>((const unsigned short*)xb, (const unsigned short*)aggb,
                                      WT1, b1, (float*)0, (unsigned short*)h1b, N, 0);
    // conv2 + linear fused: out = relu([h1 | h1@W2r+agg(h1)/deg@W2n+b2] @ lin^T + lb)
    aggregate<<<ab, 256, 0, stream>>>(h1b, aggb, rowptr, csr_src, N, 1);
    gemm_fused<<<gb, 256, 0, stream>>>((const unsigned short*)h1b, (const unsigned short*)aggb,
                                       WT2, b2, WT3, lb, out, N);
}